// Round 6
// baseline (966.016 us; speedup 1.0000x reference)
//
#include <hip/hip_runtime.h>

#define EPS  1e-5f
#define CNTF 409600.0f            // N*T*V
#define XDP_ELEMS 6553600         // per layer: 16384 nt * 400, layout [nt][u][16o]
#define Z_ELEMS   32768000        // 16384 * 2000, layout [nt][v][80ch]

__device__ __forceinline__ float wave_sum(float v) {
#pragma unroll
    for (int off = 32; off > 0; off >>= 1)
        v += __shfl_down(v, off, 64);
    return v;
}

__device__ __forceinline__ float bfu(unsigned int u16) {
    union { unsigned int i; float f; } x;
    x.i = u16 << 16;
    return x.f;
}
__device__ __forceinline__ unsigned int f2bf(float f) {
    union { float f; unsigned int i; } u; u.f = f;
    unsigned int r = u.i + 0x7fff + ((u.i >> 16) & 1);
    return r >> 16;
}

// ---- K1: conv_down all 3 layers (bias cancels in BN), bf16 xd + stats
// xdp layout: [l][p=nt*25+u][16 o]. launch_bounds(...,2): cap 256 VGPR, no spill.
__global__ __launch_bounds__(256, 2) void k_down3(
    const float* __restrict__ x, const float* __restrict__ Wd,
    unsigned short* __restrict__ xdp, float* __restrict__ st /*96*/)
{
    __shared__ float Wt[64][48];
    __shared__ float bins[96];
    const int tid = threadIdx.x;
    for (int i = tid; i < 3072; i += 256) {
        int c = i / 48, k = i - c * 48;
        int l = k / 16, o = k - l * 16;
        Wt[c][k] = Wd[l * 1024 + o * 64 + c];
    }
    if (tid < 96) bins[tid] = 0.f;
    __syncthreads();

    const int base = (blockIdx.x * 256 + tid) * 2;
    const int n = base / 3200, pb = base - n * 3200;
    const float* xb = x + n * 204800 + pb;
    float acc[2][48];
#pragma unroll
    for (int k = 0; k < 48; k++) { acc[0][k] = 0.f; acc[1][k] = 0.f; }
    for (int c = 0; c < 64; c++) {
        float2 xv = *(const float2*)&xb[c * 3200];
#pragma unroll
        for (int k = 0; k < 48; k++) {
            float wv = Wt[c][k];
            acc[0][k] += wv * xv.x;
            acc[1][k] += wv * xv.y;
        }
    }
#pragma unroll
    for (int l = 0; l < 3; l++)
#pragma unroll
        for (int j = 0; j < 2; j++) {
            unsigned int pk[8];
#pragma unroll
            for (int h = 0; h < 8; h++)
                pk[h] = f2bf(acc[j][l*16 + 2*h]) | (f2bf(acc[j][l*16 + 2*h + 1]) << 16);
            uint4* dst = (uint4*)(xdp + (size_t)l * XDP_ELEMS + (size_t)(base + j) * 16);
            dst[0] = make_uint4(pk[0], pk[1], pk[2], pk[3]);
            dst[1] = make_uint4(pk[4], pk[5], pk[6], pk[7]);
        }

    const int lane = tid & 63;
    for (int k = 0; k < 48; k++) {
        float sv = wave_sum(acc[0][k] + acc[1][k]);
        float qv = wave_sum(acc[0][k] * acc[0][k] + acc[1][k] * acc[1][k]);
        if (lane == 0) { atomicAdd(&bins[k], sv); atomicAdd(&bins[48 + k], qv); }
    }
    __syncthreads();
    if (tid < 96) atomicAdd(&st[tid], bins[tid]);
}

// ---- K2: finalize down affines
__global__ __launch_bounds__(64) void k_findown(
    const float* __restrict__ st, const float* __restrict__ gd,
    const float* __restrict__ betad, float* __restrict__ AC)
{
    int t = threadIdx.x;
    if (t < 48) {
        float m   = st[t] * (1.f / CNTF);
        float var = st[48 + t] * (1.f / CNTF) - m * m;
        float a   = gd[t] * rsqrtf(var + EPS);
        AC[t]      = a;
        AC[48 + t] = betad[t] - a * m;
    }
}

// ---- K3: per-layer z + sub BN stats; 2 channels/thread, 8 nt/block.
// 320 thr = 8 pp * 40 chp. No ztile: direct uint stores (contiguous 160B runs
// per wave per v; each block's z region is 32KB contiguous -> no L2 thrash).
// LDS ~27.6KB -> 5 blocks/CU; VGPR ~84 -> ~24 waves/CU.
__global__ __launch_bounds__(320, 4) void k_z(
    const unsigned short* __restrict__ xd, const float* __restrict__ PAl,
    const float* __restrict__ Wsl, const float* __restrict__ Al,
    const float* __restrict__ Cl, unsigned short* __restrict__ zbuf,
    float* __restrict__ stql)
{
    __shared__ float PAs[3500];               // [s][v][u pad28]
    __shared__ float xds[8][25][16];          // [pp][u][c]
    __shared__ float bins[160];
    __shared__ float As[16], Cs[16];
    const int tid = threadIdx.x;
    for (int i = tid; i < 3500; i += 320) {
        int s = i / 700, r = i - s * 700;
        int v = r / 28, u = r - v * 28;
        PAs[i] = (u < 25) ? PAl[(s * 25 + v) * 25 + u] : 0.f;
    }
    if (tid < 160) bins[tid] = 0.f;
    if (tid < 16) { As[tid] = Al[tid]; Cs[tid] = Cl[tid]; }
    __syncthreads();

    const int nt0 = blockIdx.x * 8;
    for (int i = tid; i < 400; i += 320) {
        int pp = i / 50, r = i - pp * 50;
        int u = r >> 1, half = r & 1;
        const uint4 w = *(const uint4*)(xd + (size_t)(nt0 + pp) * 400 + u * 16 + half * 8);
        float* dst = &xds[pp][u][half * 8];
        const float* A = &As[half * 8];
        const float* C = &Cs[half * 8];
        dst[0] = fmaxf(A[0] * bfu(w.x & 0xffffu) + C[0], 0.f);
        dst[1] = fmaxf(A[1] * bfu(w.x >> 16)     + C[1], 0.f);
        dst[2] = fmaxf(A[2] * bfu(w.y & 0xffffu) + C[2], 0.f);
        dst[3] = fmaxf(A[3] * bfu(w.y >> 16)     + C[3], 0.f);
        dst[4] = fmaxf(A[4] * bfu(w.z & 0xffffu) + C[4], 0.f);
        dst[5] = fmaxf(A[5] * bfu(w.z >> 16)     + C[5], 0.f);
        dst[6] = fmaxf(A[6] * bfu(w.w & 0xffffu) + C[6], 0.f);
        dst[7] = fmaxf(A[7] * bfu(w.w >> 16)     + C[7], 0.f);
    }
    __syncthreads();

    const int pp = tid / 40, q = tid - pp * 40;
    const int s = q >> 3, ch0 = s * 16 + (q & 7) * 2;
    float W0[16], W1[16];
#pragma unroll
    for (int c = 0; c < 16; c++) {
        W0[c] = Wsl[ch0 * 16 + c];
        W1[c] = Wsl[(ch0 + 1) * 16 + c];
    }

    float e0[28], e1[28];
    e0[25] = e0[26] = e0[27] = 0.f;
    e1[25] = e1[26] = e1[27] = 0.f;
#pragma unroll
    for (int u = 0; u < 25; u++) {
        const float* xr = xds[pp][u];
        float4 a0 = *(const float4*)&xr[0];
        float4 a1 = *(const float4*)&xr[4];
        float4 a2 = *(const float4*)&xr[8];
        float4 a3 = *(const float4*)&xr[12];
        e0[u] = W0[0]*a0.x + W0[1]*a0.y + W0[2]*a0.z + W0[3]*a0.w
              + W0[4]*a1.x + W0[5]*a1.y + W0[6]*a1.z + W0[7]*a1.w
              + W0[8]*a2.x + W0[9]*a2.y + W0[10]*a2.z + W0[11]*a2.w
              + W0[12]*a3.x + W0[13]*a3.y + W0[14]*a3.z + W0[15]*a3.w;
        e1[u] = W1[0]*a0.x + W1[1]*a0.y + W1[2]*a0.z + W1[3]*a0.w
              + W1[4]*a1.x + W1[5]*a1.y + W1[6]*a1.z + W1[7]*a1.w
              + W1[8]*a2.x + W1[9]*a2.y + W1[10]*a2.z + W1[11]*a2.w
              + W1[12]*a3.x + W1[13]*a3.y + W1[14]*a3.z + W1[15]*a3.w;
    }

    float s0 = 0.f, q0 = 0.f, s1 = 0.f, q1 = 0.f;
    unsigned int* zrow = (unsigned int*)(zbuf + (size_t)(nt0 + pp) * 2000);
    const int zc = ch0 >> 1;
    for (int v = 0; v < 25; v++) {
        // 4 independent partial chains for ILP
        float za0 = 0.f, zb0v = 0.f, za1 = 0.f, zb1v = 0.f;
        const float* par = &PAs[s * 700 + v * 28];
#pragma unroll
        for (int u4 = 0; u4 < 4; u4++) {
            const float4 pa = *(const float4*)&par[u4 * 4];
            za0 += pa.x*e0[4*u4] + pa.y*e0[4*u4+1] + pa.z*e0[4*u4+2] + pa.w*e0[4*u4+3];
            za1 += pa.x*e1[4*u4] + pa.y*e1[4*u4+1] + pa.z*e1[4*u4+2] + pa.w*e1[4*u4+3];
        }
#pragma unroll
        for (int u4 = 4; u4 < 7; u4++) {
            const float4 pa = *(const float4*)&par[u4 * 4];
            zb0v += pa.x*e0[4*u4] + pa.y*e0[4*u4+1] + pa.z*e0[4*u4+2] + pa.w*e0[4*u4+3];
            zb1v += pa.x*e1[4*u4] + pa.y*e1[4*u4+1] + pa.z*e1[4*u4+2] + pa.w*e1[4*u4+3];
        }
        float z0 = za0 + zb0v, z1 = za1 + zb1v;
        s0 += z0; q0 += z0 * z0;
        s1 += z1; q1 += z1 * z1;
        zrow[v * 40 + zc] = f2bf(z0) | (f2bf(z1) << 16);
    }
    atomicAdd(&bins[ch0],      s0); atomicAdd(&bins[ch0 + 1],      s1);
    atomicAdd(&bins[80 + ch0], q0); atomicAdd(&bins[80 + ch0 + 1], q1);
    __syncthreads();
    if (tid < 160) atomicAdd(&stql[tid], bins[tid]);
}

// ---- K4: apply affine + subset-0 add, RMW acc in d_out; stats on last layer
template <int FIRST, int LAST>
__global__ __launch_bounds__(256, 2) void k_apply(
    const unsigned short* __restrict__ zbuf, const float* __restrict__ stql,
    const float* __restrict__ gsl, const float* __restrict__ betal,
    float* __restrict__ out, float* __restrict__ stout)
{
    __shared__ float AS[80], CS[80];
    __shared__ float tile[32][208];
    const int tid = threadIdx.x;
    if (tid < 80) {
        float m   = stql[tid] * (1.f / CNTF);
        float var = stql[80 + tid] * (1.f / CNTF) - m * m;
        float a   = gsl[tid] * rsqrtf(var + EPS);
        AS[tid] = a; CS[tid] = betal[tid] - a * m;
    }
    __syncthreads();

    const int nt0 = blockIdx.x * 8, n = nt0 >> 7, t0 = nt0 & 127;
    float outacc[64];
    if (tid < 200) {
        const int pp = tid / 25, v = tid - pp * 25;
        const uint4* z8 = (const uint4*)(zbuf + (size_t)(nt0 + pp) * 2000 + v * 80);
        float zb0[16];
#pragma unroll
        for (int j = 0; j < 2; j++) {
            uint4 w = z8[j];
            zb0[j*8+0] = AS[j*8+0]*bfu(w.x & 0xffffu) + CS[j*8+0];
            zb0[j*8+1] = AS[j*8+1]*bfu(w.x >> 16)     + CS[j*8+1];
            zb0[j*8+2] = AS[j*8+2]*bfu(w.y & 0xffffu) + CS[j*8+2];
            zb0[j*8+3] = AS[j*8+3]*bfu(w.y >> 16)     + CS[j*8+3];
            zb0[j*8+4] = AS[j*8+4]*bfu(w.z & 0xffffu) + CS[j*8+4];
            zb0[j*8+5] = AS[j*8+5]*bfu(w.z >> 16)     + CS[j*8+5];
            zb0[j*8+6] = AS[j*8+6]*bfu(w.w & 0xffffu) + CS[j*8+6];
            zb0[j*8+7] = AS[j*8+7]*bfu(w.w >> 16)     + CS[j*8+7];
        }
#pragma unroll
        for (int j = 2; j < 10; j++) {
            uint4 w = z8[j];
            const int k = j * 8 - 16;
            outacc[k+0] = AS[16+k+0]*bfu(w.x & 0xffffu) + CS[16+k+0] + zb0[(k+0)&15];
            outacc[k+1] = AS[16+k+1]*bfu(w.x >> 16)     + CS[16+k+1] + zb0[(k+1)&15];
            outacc[k+2] = AS[16+k+2]*bfu(w.y & 0xffffu) + CS[16+k+2] + zb0[(k+2)&15];
            outacc[k+3] = AS[16+k+3]*bfu(w.y >> 16)     + CS[16+k+3] + zb0[(k+3)&15];
            outacc[k+4] = AS[16+k+4]*bfu(w.z & 0xffffu) + CS[16+k+4] + zb0[(k+4)&15];
            outacc[k+5] = AS[16+k+5]*bfu(w.z >> 16)     + CS[16+k+5] + zb0[(k+5)&15];
            outacc[k+6] = AS[16+k+6]*bfu(w.w & 0xffffu) + CS[16+k+6] + zb0[(k+6)&15];
            outacc[k+7] = AS[16+k+7]*bfu(w.w >> 16)     + CS[16+k+7] + zb0[(k+7)&15];
        }
    }
#pragma unroll
    for (int h = 0; h < 2; h++) {
        __syncthreads();
        if (tid < 200) {
#pragma unroll
            for (int kk = 0; kk < 32; kk++) tile[kk][tid] = outacc[h * 32 + kk];
        }
        __syncthreads();
        for (int i = tid; i < 6400; i += 256) {
            int kk = i / 200, p = i - kk * 200;
            int adr = n * 204800 + (h * 32 + kk) * 3200 + t0 * 25 + p;
            float val = tile[kk][p] + (FIRST ? 0.f : out[adr]);
            out[adr] = val;
            if (LAST) tile[kk][p] = val;
        }
        if (LAST) {
            __syncthreads();
            int kk = tid >> 3, c8 = tid & 7;
            float sv = 0.f, qv = 0.f;
            for (int j = 0; j < 25; j++) {
                float xv = tile[kk][c8 * 25 + j];
                sv += xv; qv += xv * xv;
            }
            sv += __shfl_down(sv, 4, 8); sv += __shfl_down(sv, 2, 8); sv += __shfl_down(sv, 1, 8);
            qv += __shfl_down(qv, 4, 8); qv += __shfl_down(qv, 2, 8); qv += __shfl_down(qv, 1, 8);
            if ((tid & 7) == 0) {
                atomicAdd(&stout[h * 32 + kk], sv);
                atomicAdd(&stout[64 + h * 32 + kk], qv);
            }
        }
    }
}

// ---- K5: out = relu(bn(acc) + x), in place on d_out
__global__ __launch_bounds__(256) void k_final(
    const float* __restrict__ x, const float* __restrict__ go,
    const float* __restrict__ bo, const float* __restrict__ stout,
    float* __restrict__ out)
{
    __shared__ float ao[64], co[64];
    const int tid = threadIdx.x;
    if (tid < 64) {
        float m   = stout[tid] * (1.f / CNTF);
        float var = stout[64 + tid] * (1.f / CNTF) - m * m;
        float a   = go[tid] * rsqrtf(var + EPS);
        ao[tid] = a; co[tid] = bo[tid] - m * a;
    }
    __syncthreads();
    const float4* x4 = (const float4*)x;
    float4* o4 = (float4*)out;
    for (int i = blockIdx.x * 256 + tid; i < 6553600; i += gridDim.x * 256) {
        int k = (i / 800) & 63;
        float a = ao[k], c = co[k];
        float4 vo = o4[i], vx = x4[i];
        vo.x = fmaxf(fmaf(a, vo.x, c) + vx.x, 0.f);
        vo.y = fmaxf(fmaf(a, vo.y, c) + vx.y, 0.f);
        vo.z = fmaxf(fmaf(a, vo.z, c) + vx.z, 0.f);
        vo.w = fmaxf(fmaf(a, vo.w, c) + vx.w, 0.f);
        o4[i] = vo;
    }
}

extern "C" void kernel_launch(void* const* d_in, const int* in_sizes, int n_in,
                              void* d_out, int out_size, void* d_ws, size_t ws_size,
                              hipStream_t stream)
{
    const float* x     = (const float*)d_in[0];
    const float* PA    = (const float*)d_in[1];
    const float* Wd    = (const float*)d_in[2];
    const float* gd    = (const float*)d_in[4];
    const float* betad = (const float*)d_in[5];
    const float* Wsub  = (const float*)d_in[6];
    const float* gsub  = (const float*)d_in[8];
    const float* betas = (const float*)d_in[9];
    const float* gout  = (const float*)d_in[10];
    const float* betao = (const float*)d_in[11];
    float* out = (float*)d_out;

    unsigned short* xdp  = (unsigned short*)d_ws;            // 39.3 MB
    unsigned short* zbuf = xdp + (size_t)3 * XDP_ELEMS;      // 65.5 MB, reused per layer
    float* st    = (float*)(zbuf + (size_t)Z_ELEMS);
    float* AC    = st + 96;
    float* stq   = AC + 96;       // [3][160]
    float* stout = stq + 480;     // [128]

    hipMemsetAsync(st, 0, 800 * sizeof(float), stream);

    k_down3  <<<800, 256, 0, stream>>>(x, Wd, xdp, st);
    k_findown<<<1,    64, 0, stream>>>(st, gd, betad, AC);

    for (int l = 0; l < 3; l++) {
        k_z<<<2048, 320, 0, stream>>>(xdp + (size_t)l * XDP_ELEMS, PA + l * 3125,
                                      Wsub + l * 1280, AC + l * 16, AC + 48 + l * 16,
                                      zbuf, stq + l * 160);
        if (l == 0)
            k_apply<1, 0><<<2048, 256, 0, stream>>>(zbuf, stq + l * 160, gsub + l * 80,
                                                    betas + l * 80, out, stout);
        else if (l == 1)
            k_apply<0, 0><<<2048, 256, 0, stream>>>(zbuf, stq + l * 160, gsub + l * 80,
                                                    betas + l * 80, out, stout);
        else
            k_apply<0, 1><<<2048, 256, 0, stream>>>(zbuf, stq + l * 160, gsub + l * 80,
                                                    betas + l * 80, out, stout);
    }
    k_final<<<2048, 256, 0, stream>>>(x, gout, betao, stout, out);
}

// Round 7
// 794.778 us; speedup vs baseline: 1.2155x; 1.2155x over previous
//
#include <hip/hip_runtime.h>

#define EPS  1e-5f
#define CNTF 409600.0f            // N*T*V
#define XDP_ELEMS 6553600         // per layer: 16384 nt * 400, layout [nt][u][16o]
#define Z_ELEMS   32768000        // 16384 * 2000, layout [nt][v][80ch]

__device__ __forceinline__ float wave_sum(float v) {
#pragma unroll
    for (int off = 32; off > 0; off >>= 1)
        v += __shfl_down(v, off, 64);
    return v;
}

__device__ __forceinline__ float bfu(unsigned int u16) {
    union { unsigned int i; float f; } x;
    x.i = u16 << 16;
    return x.f;
}
__device__ __forceinline__ unsigned int f2bf(float f) {
    union { float f; unsigned int i; } u; u.f = f;
    unsigned int r = u.i + 0x7fff + ((u.i >> 16) & 1);
    return r >> 16;
}

// ---- K0: transpose W_down into [c][48] so k_down3 can scalar-load it
__global__ __launch_bounds__(256) void k_prep(const float* __restrict__ Wd,
                                              float* __restrict__ Wtg)
{
    for (int j = threadIdx.x; j < 3072; j += 256) {
        int c = j / 48, k = j - c * 48;
        int l = k / 16, o = k - l * 16;
        Wtg[j] = Wd[l * 1024 + o * 64 + c];
    }
}

// ---- K1: conv_down all 3 layers (bias cancels in BN), bf16 xd + stats.
// W read via thread-uniform addresses -> s_load (SGPR broadcast, no LDS stream).
// All per-thread arrays statically indexed (every loop unrolled): no scratch.
__global__ __launch_bounds__(256) void k_down3(
    const float* __restrict__ x, const float* __restrict__ Wtg,
    unsigned short* __restrict__ xdp, float* __restrict__ st /*96*/)
{
    __shared__ float bins[96];
    const int tid = threadIdx.x;
    if (tid < 96) bins[tid] = 0.f;
    __syncthreads();

    const int base = (blockIdx.x * 256 + tid) * 2;
    const int n = base / 3200, pb = base - n * 3200;
    const float* xb = x + n * 204800 + pb;

    float acc0[48], acc1[48];
#pragma unroll
    for (int k = 0; k < 48; k++) { acc0[k] = 0.f; acc1[k] = 0.f; }

    for (int c = 0; c < 64; c++) {
        float2 xv = *(const float2*)&xb[c * 3200];
        const float4* wr = (const float4*)(Wtg + c * 48);   // uniform -> s_load
#pragma unroll
        for (int q = 0; q < 12; q++) {
            float4 w = wr[q];
            acc0[4*q+0] += w.x * xv.x;  acc1[4*q+0] += w.x * xv.y;
            acc0[4*q+1] += w.y * xv.x;  acc1[4*q+1] += w.y * xv.y;
            acc0[4*q+2] += w.z * xv.x;  acc1[4*q+2] += w.z * xv.y;
            acc0[4*q+3] += w.w * xv.x;  acc1[4*q+3] += w.w * xv.y;
        }
    }
#pragma unroll
    for (int l = 0; l < 3; l++) {
        unsigned int pk0[8], pk1[8];
#pragma unroll
        for (int h = 0; h < 8; h++) {
            pk0[h] = f2bf(acc0[l*16 + 2*h]) | (f2bf(acc0[l*16 + 2*h + 1]) << 16);
            pk1[h] = f2bf(acc1[l*16 + 2*h]) | (f2bf(acc1[l*16 + 2*h + 1]) << 16);
        }
        uint4* dst = (uint4*)(xdp + (size_t)l * XDP_ELEMS + (size_t)base * 16);
        dst[0] = make_uint4(pk0[0], pk0[1], pk0[2], pk0[3]);
        dst[1] = make_uint4(pk0[4], pk0[5], pk0[6], pk0[7]);
        dst[2] = make_uint4(pk1[0], pk1[1], pk1[2], pk1[3]);
        dst[3] = make_uint4(pk1[4], pk1[5], pk1[6], pk1[7]);
    }

    const int lane = tid & 63;
#pragma unroll
    for (int k = 0; k < 48; k++) {
        float sv = wave_sum(acc0[k] + acc1[k]);
        float qv = wave_sum(acc0[k] * acc0[k] + acc1[k] * acc1[k]);
        if (lane == 0) { atomicAdd(&bins[k], sv); atomicAdd(&bins[48 + k], qv); }
    }
    __syncthreads();
    if (tid < 96) atomicAdd(&st[tid], bins[tid]);
}

// ---- K2: finalize down affines
__global__ __launch_bounds__(64) void k_findown(
    const float* __restrict__ st, const float* __restrict__ gd,
    const float* __restrict__ betad, float* __restrict__ AC)
{
    int t = threadIdx.x;
    if (t < 48) {
        float m   = st[t] * (1.f / CNTF);
        float var = st[48 + t] * (1.f / CNTF) - m * m;
        float a   = gd[t] * rsqrtf(var + EPS);
        AC[t]      = a;
        AC[48 + t] = betad[t] - a * m;
    }
}

// ---- K3: per-layer z + sub BN stats; 2 channels/thread, 8 nt/block.
// (320,2): empirically 84 VGPR, no spill. LDS ~27.6KB.
__global__ __launch_bounds__(320, 2) void k_z(
    const unsigned short* __restrict__ xd, const float* __restrict__ PAl,
    const float* __restrict__ Wsl, const float* __restrict__ Al,
    const float* __restrict__ Cl, unsigned short* __restrict__ zbuf,
    float* __restrict__ stql)
{
    __shared__ float PAs[3500];               // [s][v][u pad28]
    __shared__ float xds[8][25][16];          // [pp][u][c]
    __shared__ float bins[160];
    __shared__ float As[16], Cs[16];
    const int tid = threadIdx.x;
    for (int i = tid; i < 3500; i += 320) {
        int s = i / 700, r = i - s * 700;
        int v = r / 28, u = r - v * 28;
        PAs[i] = (u < 25) ? PAl[(s * 25 + v) * 25 + u] : 0.f;
    }
    if (tid < 160) bins[tid] = 0.f;
    if (tid < 16) { As[tid] = Al[tid]; Cs[tid] = Cl[tid]; }
    __syncthreads();

    const int nt0 = blockIdx.x * 8;
    for (int i = tid; i < 400; i += 320) {
        int pp = i / 50, r = i - pp * 50;
        int u = r >> 1, half = r & 1;
        const uint4 w = *(const uint4*)(xd + (size_t)(nt0 + pp) * 400 + u * 16 + half * 8);
        float* dst = &xds[pp][u][half * 8];
        const float* A = &As[half * 8];
        const float* C = &Cs[half * 8];
        dst[0] = fmaxf(A[0] * bfu(w.x & 0xffffu) + C[0], 0.f);
        dst[1] = fmaxf(A[1] * bfu(w.x >> 16)     + C[1], 0.f);
        dst[2] = fmaxf(A[2] * bfu(w.y & 0xffffu) + C[2], 0.f);
        dst[3] = fmaxf(A[3] * bfu(w.y >> 16)     + C[3], 0.f);
        dst[4] = fmaxf(A[4] * bfu(w.z & 0xffffu) + C[4], 0.f);
        dst[5] = fmaxf(A[5] * bfu(w.z >> 16)     + C[5], 0.f);
        dst[6] = fmaxf(A[6] * bfu(w.w & 0xffffu) + C[6], 0.f);
        dst[7] = fmaxf(A[7] * bfu(w.w >> 16)     + C[7], 0.f);
    }
    __syncthreads();

    const int pp = tid / 40, q = tid - pp * 40;
    const int s = q >> 3, ch0 = s * 16 + (q & 7) * 2;
    float W0[16], W1[16];
#pragma unroll
    for (int c = 0; c < 16; c++) {
        W0[c] = Wsl[ch0 * 16 + c];
        W1[c] = Wsl[(ch0 + 1) * 16 + c];
    }

    float e0[28], e1[28];
    e0[25] = e0[26] = e0[27] = 0.f;
    e1[25] = e1[26] = e1[27] = 0.f;
#pragma unroll
    for (int u = 0; u < 25; u++) {
        const float* xr = xds[pp][u];
        float4 a0 = *(const float4*)&xr[0];
        float4 a1 = *(const float4*)&xr[4];
        float4 a2 = *(const float4*)&xr[8];
        float4 a3 = *(const float4*)&xr[12];
        e0[u] = W0[0]*a0.x + W0[1]*a0.y + W0[2]*a0.z + W0[3]*a0.w
              + W0[4]*a1.x + W0[5]*a1.y + W0[6]*a1.z + W0[7]*a1.w
              + W0[8]*a2.x + W0[9]*a2.y + W0[10]*a2.z + W0[11]*a2.w
              + W0[12]*a3.x + W0[13]*a3.y + W0[14]*a3.z + W0[15]*a3.w;
        e1[u] = W1[0]*a0.x + W1[1]*a0.y + W1[2]*a0.z + W1[3]*a0.w
              + W1[4]*a1.x + W1[5]*a1.y + W1[6]*a1.z + W1[7]*a1.w
              + W1[8]*a2.x + W1[9]*a2.y + W1[10]*a2.z + W1[11]*a2.w
              + W1[12]*a3.x + W1[13]*a3.y + W1[14]*a3.z + W1[15]*a3.w;
    }

    float s0 = 0.f, q0 = 0.f, s1 = 0.f, q1 = 0.f;
    unsigned int* zrow = (unsigned int*)(zbuf + (size_t)(nt0 + pp) * 2000);
    const int zc = ch0 >> 1;
    for (int v = 0; v < 25; v++) {
        float za0 = 0.f, zb0v = 0.f, za1 = 0.f, zb1v = 0.f;
        const float* par = &PAs[s * 700 + v * 28];
#pragma unroll
        for (int u4 = 0; u4 < 4; u4++) {
            const float4 pa = *(const float4*)&par[u4 * 4];
            za0 += pa.x*e0[4*u4] + pa.y*e0[4*u4+1] + pa.z*e0[4*u4+2] + pa.w*e0[4*u4+3];
            za1 += pa.x*e1[4*u4] + pa.y*e1[4*u4+1] + pa.z*e1[4*u4+2] + pa.w*e1[4*u4+3];
        }
#pragma unroll
        for (int u4 = 4; u4 < 7; u4++) {
            const float4 pa = *(const float4*)&par[u4 * 4];
            zb0v += pa.x*e0[4*u4] + pa.y*e0[4*u4+1] + pa.z*e0[4*u4+2] + pa.w*e0[4*u4+3];
            zb1v += pa.x*e1[4*u4] + pa.y*e1[4*u4+1] + pa.z*e1[4*u4+2] + pa.w*e1[4*u4+3];
        }
        float z0 = za0 + zb0v, z1 = za1 + zb1v;
        s0 += z0; q0 += z0 * z0;
        s1 += z1; q1 += z1 * z1;
        zrow[v * 40 + zc] = f2bf(z0) | (f2bf(z1) << 16);
    }
    atomicAdd(&bins[ch0],      s0); atomicAdd(&bins[ch0 + 1],      s1);
    atomicAdd(&bins[80 + ch0], q0); atomicAdd(&bins[80 + ch0 + 1], q1);
    __syncthreads();
    if (tid < 160) atomicAdd(&stql[tid], bins[tid]);
}

// ---- K4: apply affine + subset-0 add, RMW acc in d_out; stats on last layer
template <int FIRST, int LAST>
__global__ __launch_bounds__(256, 2) void k_apply(
    const unsigned short* __restrict__ zbuf, const float* __restrict__ stql,
    const float* __restrict__ gsl, const float* __restrict__ betal,
    float* __restrict__ out, float* __restrict__ stout)
{
    __shared__ float AS[80], CS[80];
    __shared__ float tile[32][208];
    const int tid = threadIdx.x;
    if (tid < 80) {
        float m   = stql[tid] * (1.f / CNTF);
        float var = stql[80 + tid] * (1.f / CNTF) - m * m;
        float a   = gsl[tid] * rsqrtf(var + EPS);
        AS[tid] = a; CS[tid] = betal[tid] - a * m;
    }
    __syncthreads();

    const int nt0 = blockIdx.x * 8, n = nt0 >> 7, t0 = nt0 & 127;
    float outacc[64];
    if (tid < 200) {
        const int pp = tid / 25, v = tid - pp * 25;
        const uint4* z8 = (const uint4*)(zbuf + (size_t)(nt0 + pp) * 2000 + v * 80);
        float zb0[16];
#pragma unroll
        for (int j = 0; j < 2; j++) {
            uint4 w = z8[j];
            zb0[j*8+0] = AS[j*8+0]*bfu(w.x & 0xffffu) + CS[j*8+0];
            zb0[j*8+1] = AS[j*8+1]*bfu(w.x >> 16)     + CS[j*8+1];
            zb0[j*8+2] = AS[j*8+2]*bfu(w.y & 0xffffu) + CS[j*8+2];
            zb0[j*8+3] = AS[j*8+3]*bfu(w.y >> 16)     + CS[j*8+3];
            zb0[j*8+4] = AS[j*8+4]*bfu(w.z & 0xffffu) + CS[j*8+4];
            zb0[j*8+5] = AS[j*8+5]*bfu(w.z >> 16)     + CS[j*8+5];
            zb0[j*8+6] = AS[j*8+6]*bfu(w.w & 0xffffu) + CS[j*8+6];
            zb0[j*8+7] = AS[j*8+7]*bfu(w.w >> 16)     + CS[j*8+7];
        }
#pragma unroll
        for (int j = 2; j < 10; j++) {
            uint4 w = z8[j];
            const int k = j * 8 - 16;
            outacc[k+0] = AS[16+k+0]*bfu(w.x & 0xffffu) + CS[16+k+0] + zb0[(k+0)&15];
            outacc[k+1] = AS[16+k+1]*bfu(w.x >> 16)     + CS[16+k+1] + zb0[(k+1)&15];
            outacc[k+2] = AS[16+k+2]*bfu(w.y & 0xffffu) + CS[16+k+2] + zb0[(k+2)&15];
            outacc[k+3] = AS[16+k+3]*bfu(w.y >> 16)     + CS[16+k+3] + zb0[(k+3)&15];
            outacc[k+4] = AS[16+k+4]*bfu(w.z & 0xffffu) + CS[16+k+4] + zb0[(k+4)&15];
            outacc[k+5] = AS[16+k+5]*bfu(w.z >> 16)     + CS[16+k+5] + zb0[(k+5)&15];
            outacc[k+6] = AS[16+k+6]*bfu(w.w & 0xffffu) + CS[16+k+6] + zb0[(k+6)&15];
            outacc[k+7] = AS[16+k+7]*bfu(w.w >> 16)     + CS[16+k+7] + zb0[(k+7)&15];
        }
    }
#pragma unroll
    for (int h = 0; h < 2; h++) {
        __syncthreads();
        if (tid < 200) {
#pragma unroll
            for (int kk = 0; kk < 32; kk++) tile[kk][tid] = outacc[h * 32 + kk];
        }
        __syncthreads();
        for (int i = tid; i < 6400; i += 256) {
            int kk = i / 200, p = i - kk * 200;
            int adr = n * 204800 + (h * 32 + kk) * 3200 + t0 * 25 + p;
            float val = tile[kk][p] + (FIRST ? 0.f : out[adr]);
            out[adr] = val;
            if (LAST) tile[kk][p] = val;
        }
        if (LAST) {
            __syncthreads();
            int kk = tid >> 3, c8 = tid & 7;
            float sv = 0.f, qv = 0.f;
            for (int j = 0; j < 25; j++) {
                float xv = tile[kk][c8 * 25 + j];
                sv += xv; qv += xv * xv;
            }
            sv += __shfl_down(sv, 4, 8); sv += __shfl_down(sv, 2, 8); sv += __shfl_down(sv, 1, 8);
            qv += __shfl_down(qv, 4, 8); qv += __shfl_down(qv, 2, 8); qv += __shfl_down(qv, 1, 8);
            if ((tid & 7) == 0) {
                atomicAdd(&stout[h * 32 + kk], sv);
                atomicAdd(&stout[64 + h * 32 + kk], qv);
            }
        }
    }
}

// ---- K5: out = relu(bn(acc) + x), in place on d_out
__global__ __launch_bounds__(256) void k_final(
    const float* __restrict__ x, const float* __restrict__ go,
    const float* __restrict__ bo, const float* __restrict__ stout,
    float* __restrict__ out)
{
    __shared__ float ao[64], co[64];
    const int tid = threadIdx.x;
    if (tid < 64) {
        float m   = stout[tid] * (1.f / CNTF);
        float var = stout[64 + tid] * (1.f / CNTF) - m * m;
        float a   = go[tid] * rsqrtf(var + EPS);
        ao[tid] = a; co[tid] = bo[tid] - m * a;
    }
    __syncthreads();
    const float4* x4 = (const float4*)x;
    float4* o4 = (float4*)out;
    for (int i = blockIdx.x * 256 + tid; i < 6553600; i += gridDim.x * 256) {
        int k = (i / 800) & 63;
        float a = ao[k], c = co[k];
        float4 vo = o4[i], vx = x4[i];
        vo.x = fmaxf(fmaf(a, vo.x, c) + vx.x, 0.f);
        vo.y = fmaxf(fmaf(a, vo.y, c) + vx.y, 0.f);
        vo.z = fmaxf(fmaf(a, vo.z, c) + vx.z, 0.f);
        vo.w = fmaxf(fmaf(a, vo.w, c) + vx.w, 0.f);
        o4[i] = vo;
    }
}

extern "C" void kernel_launch(void* const* d_in, const int* in_sizes, int n_in,
                              void* d_out, int out_size, void* d_ws, size_t ws_size,
                              hipStream_t stream)
{
    const float* x     = (const float*)d_in[0];
    const float* PA    = (const float*)d_in[1];
    const float* Wd    = (const float*)d_in[2];
    const float* gd    = (const float*)d_in[4];
    const float* betad = (const float*)d_in[5];
    const float* Wsub  = (const float*)d_in[6];
    const float* gsub  = (const float*)d_in[8];
    const float* betas = (const float*)d_in[9];
    const float* gout  = (const float*)d_in[10];
    const float* betao = (const float*)d_in[11];
    float* out = (float*)d_out;

    unsigned short* xdp  = (unsigned short*)d_ws;            // 39.3 MB
    unsigned short* zbuf = xdp + (size_t)3 * XDP_ELEMS;      // 65.5 MB, reused per layer
    float* st    = (float*)(zbuf + (size_t)Z_ELEMS);
    float* AC    = st + 96;
    float* stq   = AC + 96;       // [3][160]
    float* stout = stq + 480;     // [128]
    float* Wtg   = stout + 128;   // [64][48] transposed W_down

    hipMemsetAsync(st, 0, 800 * sizeof(float), stream);

    k_prep   <<<1,   256, 0, stream>>>(Wd, Wtg);
    k_down3  <<<800, 256, 0, stream>>>(x, Wtg, xdp, st);
    k_findown<<<1,    64, 0, stream>>>(st, gd, betad, AC);

    for (int l = 0; l < 3; l++) {
        k_z<<<2048, 320, 0, stream>>>(xdp + (size_t)l * XDP_ELEMS, PA + l * 3125,
                                      Wsub + l * 1280, AC + l * 16, AC + 48 + l * 16,
                                      zbuf, stq + l * 160);
        if (l == 0)
            k_apply<1, 0><<<2048, 256, 0, stream>>>(zbuf, stq + l * 160, gsub + l * 80,
                                                    betas + l * 80, out, stout);
        else if (l == 1)
            k_apply<0, 0><<<2048, 256, 0, stream>>>(zbuf, stq + l * 160, gsub + l * 80,
                                                    betas + l * 80, out, stout);
        else
            k_apply<0, 1><<<2048, 256, 0, stream>>>(zbuf, stq + l * 160, gsub + l * 80,
                                                    betas + l * 80, out, stout);
    }
    k_final<<<2048, 256, 0, stream>>>(x, gout, betao, stout, out);
}

// Round 9
// 527.480 us; speedup vs baseline: 1.8314x; 1.5067x over previous
//
#include <hip/hip_runtime.h>

#define EPS  1e-5f
#define CNTF 409600.0f            // N*T*V
#define XDP_ELEMS 6553600         // per layer: 16384 nt * 400, layout [nt][u][16o]
#define Z_ELEMS   32768000        // 16384 * 2000, layout [nt][v][80ch]

typedef short bf16x8 __attribute__((ext_vector_type(8)));
typedef float f32x4  __attribute__((ext_vector_type(4)));

union FRAG { unsigned int u[4]; bf16x8 v; };

__device__ __forceinline__ float wave_sum(float v) {
#pragma unroll
    for (int off = 32; off > 0; off >>= 1)
        v += __shfl_down(v, off, 64);
    return v;
}

__device__ __forceinline__ float bfu(unsigned int u16) {
    union { unsigned int i; float f; } x;
    x.i = u16 << 16;
    return x.f;
}
__device__ __forceinline__ unsigned int f2bf(float f) {
    union { float f; unsigned int i; } u; u.f = f;
    unsigned int r = u.i + 0x7fff + ((u.i >> 16) & 1);
    return r >> 16;
}
__device__ __forceinline__ unsigned int packbf(float a, float b) {
    return f2bf(a) | (f2bf(b) << 16);
}

// ---- K0: transpose W_down into [c][48] so k_down3 can scalar-load it
__global__ __launch_bounds__(256) void k_prep(const float* __restrict__ Wd,
                                              float* __restrict__ Wtg)
{
    for (int j = threadIdx.x; j < 3072; j += 256) {
        int c = j / 48, k = j - c * 48;
        int l = k / 16, o = k - l * 16;
        Wtg[j] = Wd[l * 1024 + o * 64 + c];
    }
}

// ---- K1: conv_down all 3 layers (bias cancels in BN), bf16 xd + stats.
__global__ __launch_bounds__(256) void k_down3(
    const float* __restrict__ x, const float* __restrict__ Wtg,
    unsigned short* __restrict__ xdp, float* __restrict__ st /*96*/)
{
    __shared__ float bins[96];
    const int tid = threadIdx.x;
    if (tid < 96) bins[tid] = 0.f;
    __syncthreads();

    const int base = (blockIdx.x * 256 + tid) * 2;
    const int n = base / 3200, pb = base - n * 3200;
    const float* xb = x + n * 204800 + pb;

    float acc0[48], acc1[48];
#pragma unroll
    for (int k = 0; k < 48; k++) { acc0[k] = 0.f; acc1[k] = 0.f; }

    for (int c = 0; c < 64; c++) {
        float2 xv = *(const float2*)&xb[c * 3200];
        const float4* wr = (const float4*)(Wtg + c * 48);   // uniform -> s_load
#pragma unroll
        for (int q = 0; q < 12; q++) {
            float4 w = wr[q];
            acc0[4*q+0] += w.x * xv.x;  acc1[4*q+0] += w.x * xv.y;
            acc0[4*q+1] += w.y * xv.x;  acc1[4*q+1] += w.y * xv.y;
            acc0[4*q+2] += w.z * xv.x;  acc1[4*q+2] += w.z * xv.y;
            acc0[4*q+3] += w.w * xv.x;  acc1[4*q+3] += w.w * xv.y;
        }
    }
#pragma unroll
    for (int l = 0; l < 3; l++) {
        unsigned int pk0[8], pk1[8];
#pragma unroll
        for (int h = 0; h < 8; h++) {
            pk0[h] = packbf(acc0[l*16 + 2*h], acc0[l*16 + 2*h + 1]);
            pk1[h] = packbf(acc1[l*16 + 2*h], acc1[l*16 + 2*h + 1]);
        }
        uint4* dst = (uint4*)(xdp + (size_t)l * XDP_ELEMS + (size_t)base * 16);
        dst[0] = make_uint4(pk0[0], pk0[1], pk0[2], pk0[3]);
        dst[1] = make_uint4(pk0[4], pk0[5], pk0[6], pk0[7]);
        dst[2] = make_uint4(pk1[0], pk1[1], pk1[2], pk1[3]);
        dst[3] = make_uint4(pk1[4], pk1[5], pk1[6], pk1[7]);
    }

    const int lane = tid & 63;
#pragma unroll
    for (int k = 0; k < 48; k++) {
        float sv = wave_sum(acc0[k] + acc1[k]);
        float qv = wave_sum(acc0[k] * acc0[k] + acc1[k] * acc1[k]);
        if (lane == 0) { atomicAdd(&bins[k], sv); atomicAdd(&bins[48 + k], qv); }
    }
    __syncthreads();
    if (tid < 96) atomicAdd(&st[tid], bins[tid]);
}

// ---- K2: finalize down affines
__global__ __launch_bounds__(64) void k_findown(
    const float* __restrict__ st, const float* __restrict__ gd,
    const float* __restrict__ betad, float* __restrict__ AC)
{
    int t = threadIdx.x;
    if (t < 48) {
        float m   = st[t] * (1.f / CNTF);
        float var = st[48 + t] * (1.f / CNTF) - m * m;
        float a   = gd[t] * rsqrtf(var + EPS);
        AC[t]      = a;
        AC[48 + t] = betad[t] - a * m;
    }
}

// ---- K3 (MFMA): per-layer z + sub BN stats.
// M_s = relu(affine(XD)) . PA_s^T  then  Z_s = W_s . M_s (LDS reshape between).
// xtile fully zero-initialized: K-pad slots (u>=25) are finite 0, so the
// zero-padded PA/W fragments guarantee pad products are exactly 0 (no Inf*0).
__global__ __launch_bounds__(256, 1) void k_z_mfma(
    const unsigned short* __restrict__ xd,   // [nt][u<25][16c] bf16
    const float* __restrict__ PAl,           // [5][25][25]
    const float* __restrict__ Wsl,           // [80][16]
    const float* __restrict__ Al, const float* __restrict__ Cl,
    unsigned short* __restrict__ zbuf,       // [nt][v<25][80] bf16
    float* __restrict__ stql)                // [160]
{
    __shared__ unsigned short xtile[4][512];      // per-wave raw xd tile (u<=31 x 16c)
    __shared__ unsigned short Mtile[4][32][16];   // per-wave M reshape [v][c]
    __shared__ float bins[160];

    const int tid  = threadIdx.x;
    const int wave = tid >> 6, lane = tid & 63;
    const int lr = lane & 15, lg = lane >> 4;

    // zero ALL of xtile once (tail u>=25 stays 0 forever)
    *(uint4*)&xtile[tid >> 6][(tid & 63) * 8] = make_uint4(0, 0, 0, 0);
    for (int i = tid; i < 160; i += 256) bins[i] = 0.f;
    __syncthreads();

    // persistent B fragments: B(lg,i) = PA[s][v=16t+lr][u=8*lg+i], 0 if oob
    bf16x8 Bfrag[5][2];
#pragma unroll
    for (int s = 0; s < 5; s++)
#pragma unroll
        for (int t = 0; t < 2; t++) {
            FRAG f;
            const int v = t * 16 + lr;
#pragma unroll
            for (int h = 0; h < 4; h++) {
                int u0 = 8 * lg + 2 * h, u1 = u0 + 1;
                float f0 = (v < 25 && u0 < 25) ? PAl[(s * 25 + v) * 25 + u0] : 0.f;
                float f1 = (v < 25 && u1 < 25) ? PAl[(s * 25 + v) * 25 + u1] : 0.f;
                f.u[h] = packbf(f0, f1);
            }
            Bfrag[s][t] = f.v;
        }

    // persistent W fragments: A2(lg,i) = W[s][o=lr][c=8*lg+i], 0 if c>=16
    bf16x8 Wfrag[5];
#pragma unroll
    for (int s = 0; s < 5; s++) {
        FRAG f;
#pragma unroll
        for (int h = 0; h < 4; h++) {
            int c0 = 8 * lg + 2 * h, c1 = c0 + 1;
            float f0 = (c0 < 16) ? Wsl[(s * 16 + lr) * 16 + c0] : 0.f;
            float f1 = (c1 < 16) ? Wsl[(s * 16 + lr) * 16 + c1] : 0.f;
            f.u[h] = packbf(f0, f1);
        }
        Wfrag[s] = f.v;
    }

    const float a_c = Al[lr], c_c = Cl[lr];   // down-BN affine for channel c=lr

    f32x4 sacc[5] = {};
    f32x4 qacc[5] = {};
    const f32x4 zero = {};

    const int wid = blockIdx.x * 4 + wave;    // 4096 waves x 4 nt = 16384
    for (int k = 0; k < 4; k++) {
        const int nt = wid * 4 + k;
        // stage one nt (800B) into the wave's private tile
        if (lane < 50)
            *(uint4*)&xtile[wave][lane * 8] =
                *(const uint4*)(xd + (size_t)nt * 400 + lane * 8);
        __syncthreads();   // staging visible (uniform: all waves, all k)

        // A fragment: lane holds c=lr, u=8*lg+i
        FRAG af;
#pragma unroll
        for (int h = 0; h < 4; h++) {
            int u0 = 8 * lg + 2 * h;
            float x0 = bfu(xtile[wave][u0 * 16 + lr]);
            float x1 = bfu(xtile[wave][(u0 + 1) * 16 + lr]);
            x0 = fmaxf(a_c * x0 + c_c, 0.f);
            x1 = fmaxf(a_c * x1 + c_c, 0.f);
            af.u[h] = packbf(x0, x1);
        }
        const bf16x8 A = af.v;
        unsigned short* zrow = zbuf + (size_t)nt * 2000;

#pragma unroll
        for (int s = 0; s < 5; s++) {
            // step A: M_s tiles (D: col=v=lr, row=c=4*lg+r)
            f32x4 d0 = __builtin_amdgcn_mfma_f32_16x16x32_bf16(A, Bfrag[s][0], zero, 0, 0, 0);
            f32x4 d1 = __builtin_amdgcn_mfma_f32_16x16x32_bf16(A, Bfrag[s][1], zero, 0, 0, 0);
            // reshape via LDS: M [v][c] bf16
            *(uint2*)&Mtile[wave][lr][4 * lg] =
                make_uint2(packbf(d0[0], d0[1]), packbf(d0[2], d0[3]));
            *(uint2*)&Mtile[wave][16 + lr][4 * lg] =
                make_uint2(packbf(d1[0], d1[1]), packbf(d1[2], d1[3]));
            __syncthreads();   // writes -> reads
            // B2: lane holds v=16t+lr, c=8*(lg&1)+i (c>=16 slots: Wfrag zero)
            FRAG b2a, b2b;
            *(uint4*)b2a.u = *(const uint4*)&Mtile[wave][lr][8 * (lg & 1)];
            *(uint4*)b2b.u = *(const uint4*)&Mtile[wave][16 + lr][8 * (lg & 1)];
            __syncthreads();   // reads done before next s overwrites (WAR)
            // step B: Z_s (D: col=v, row=o=4*lg+r)
            f32x4 z0 = __builtin_amdgcn_mfma_f32_16x16x32_bf16(Wfrag[s], b2a.v, zero, 0, 0, 0);
            f32x4 z1 = __builtin_amdgcn_mfma_f32_16x16x32_bf16(Wfrag[s], b2b.v, zero, 0, 0, 0);

            sacc[s] += z0; qacc[s] += z0 * z0;
            unsigned short* zp = zrow + lr * 80 + s * 16 + 4 * lg;
            *(uint2*)zp = make_uint2(packbf(z0[0], z0[1]), packbf(z0[2], z0[3]));
            if (lr < 9) {                         // tile2 valid v = 16..24
                sacc[s] += z1; qacc[s] += z1 * z1;
                *(uint2*)(zp + 1280) =
                    make_uint2(packbf(z1[0], z1[1]), packbf(z1[2], z1[3]));
            }
        }
    }

    // stats: reduce over the 16 v-lanes, then block bins, then global
#pragma unroll
    for (int s = 0; s < 5; s++)
#pragma unroll
        for (int r = 0; r < 4; r++) {
            float sv = sacc[s][r], qv = qacc[s][r];
            sv += __shfl_xor(sv, 1, 64); qv += __shfl_xor(qv, 1, 64);
            sv += __shfl_xor(sv, 2, 64); qv += __shfl_xor(qv, 2, 64);
            sv += __shfl_xor(sv, 4, 64); qv += __shfl_xor(qv, 4, 64);
            sv += __shfl_xor(sv, 8, 64); qv += __shfl_xor(qv, 8, 64);
            if (lr == 0) {
                atomicAdd(&bins[s * 16 + 4 * lg + r], sv);
                atomicAdd(&bins[80 + s * 16 + 4 * lg + r], qv);
            }
        }
    __syncthreads();
    for (int i = tid; i < 160; i += 256) atomicAdd(&stql[i], bins[i]);
}

// ---- K4: apply affine + subset-0 add, RMW acc in d_out; stats on last layer
template <int FIRST, int LAST>
__global__ __launch_bounds__(256, 2) void k_apply(
    const unsigned short* __restrict__ zbuf, const float* __restrict__ stql,
    const float* __restrict__ gsl, const float* __restrict__ betal,
    float* __restrict__ out, float* __restrict__ stout)
{
    __shared__ float AS[80], CS[80];
    __shared__ float tile[32][208];
    const int tid = threadIdx.x;
    if (tid < 80) {
        float m   = stql[tid] * (1.f / CNTF);
        float var = stql[80 + tid] * (1.f / CNTF) - m * m;
        float a   = gsl[tid] * rsqrtf(var + EPS);
        AS[tid] = a; CS[tid] = betal[tid] - a * m;
    }
    __syncthreads();

    const int nt0 = blockIdx.x * 8, n = nt0 >> 7, t0 = nt0 & 127;
    float outacc[64];
    if (tid < 200) {
        const int pp = tid / 25, v = tid - pp * 25;
        const uint4* z8 = (const uint4*)(zbuf + (size_t)(nt0 + pp) * 2000 + v * 80);
        float zb0[16];
#pragma unroll
        for (int j = 0; j < 2; j++) {
            uint4 w = z8[j];
            zb0[j*8+0] = AS[j*8+0]*bfu(w.x & 0xffffu) + CS[j*8+0];
            zb0[j*8+1] = AS[j*8+1]*bfu(w.x >> 16)     + CS[j*8+1];
            zb0[j*8+2] = AS[j*8+2]*bfu(w.y & 0xffffu) + CS[j*8+2];
            zb0[j*8+3] = AS[j*8+3]*bfu(w.y >> 16)     + CS[j*8+3];
            zb0[j*8+4] = AS[j*8+4]*bfu(w.z & 0xffffu) + CS[j*8+4];
            zb0[j*8+5] = AS[j*8+5]*bfu(w.z >> 16)     + CS[j*8+5];
            zb0[j*8+6] = AS[j*8+6]*bfu(w.w & 0xffffu) + CS[j*8+6];
            zb0[j*8+7] = AS[j*8+7]*bfu(w.w >> 16)     + CS[j*8+7];
        }
#pragma unroll
        for (int j = 2; j < 10; j++) {
            uint4 w = z8[j];
            const int k = j * 8 - 16;
            outacc[k+0] = AS[16+k+0]*bfu(w.x & 0xffffu) + CS[16+k+0] + zb0[(k+0)&15];
            outacc[k+1] = AS[16+k+1]*bfu(w.x >> 16)     + CS[16+k+1] + zb0[(k+1)&15];
            outacc[k+2] = AS[16+k+2]*bfu(w.y & 0xffffu) + CS[16+k+2] + zb0[(k+2)&15];
            outacc[k+3] = AS[16+k+3]*bfu(w.y >> 16)     + CS[16+k+3] + zb0[(k+3)&15];
            outacc[k+4] = AS[16+k+4]*bfu(w.z & 0xffffu) + CS[16+k+4] + zb0[(k+4)&15];
            outacc[k+5] = AS[16+k+5]*bfu(w.z >> 16)     + CS[16+k+5] + zb0[(k+5)&15];
            outacc[k+6] = AS[16+k+6]*bfu(w.w & 0xffffu) + CS[16+k+6] + zb0[(k+6)&15];
            outacc[k+7] = AS[16+k+7]*bfu(w.w >> 16)     + CS[16+k+7] + zb0[(k+7)&15];
        }
    }
#pragma unroll
    for (int h = 0; h < 2; h++) {
        __syncthreads();
        if (tid < 200) {
#pragma unroll
            for (int kk = 0; kk < 32; kk++) tile[kk][tid] = outacc[h * 32 + kk];
        }
        __syncthreads();
        for (int i = tid; i < 6400; i += 256) {
            int kk = i / 200, p = i - kk * 200;
            int adr = n * 204800 + (h * 32 + kk) * 3200 + t0 * 25 + p;
            float val = tile[kk][p] + (FIRST ? 0.f : out[adr]);
            out[adr] = val;
            if (LAST) tile[kk][p] = val;
        }
        if (LAST) {
            __syncthreads();
            int kk = tid >> 3, c8 = tid & 7;
            float sv = 0.f, qv = 0.f;
            for (int j = 0; j < 25; j++) {
                float xv = tile[kk][c8 * 25 + j];
                sv += xv; qv += xv * xv;
            }
            sv += __shfl_down(sv, 4, 8); sv += __shfl_down(sv, 2, 8); sv += __shfl_down(sv, 1, 8);
            qv += __shfl_down(qv, 4, 8); qv += __shfl_down(qv, 2, 8); qv += __shfl_down(qv, 1, 8);
            if ((tid & 7) == 0) {
                atomicAdd(&stout[h * 32 + kk], sv);
                atomicAdd(&stout[64 + h * 32 + kk], qv);
            }
        }
    }
}

// ---- K5: out = relu(bn(acc) + x), in place on d_out
__global__ __launch_bounds__(256) void k_final(
    const float* __restrict__ x, const float* __restrict__ go,
    const float* __restrict__ bo, const float* __restrict__ stout,
    float* __restrict__ out)
{
    __shared__ float ao[64], co[64];
    const int tid = threadIdx.x;
    if (tid < 64) {
        float m   = stout[tid] * (1.f / CNTF);
        float var = stout[64 + tid] * (1.f / CNTF) - m * m;
        float a   = go[tid] * rsqrtf(var + EPS);
        ao[tid] = a; co[tid] = bo[tid] - m * a;
    }
    __syncthreads();
    const float4* x4 = (const float4*)x;
    float4* o4 = (float4*)out;
    for (int i = blockIdx.x * 256 + tid; i < 6553600; i += gridDim.x * 256) {
        int k = (i / 800) & 63;
        float a = ao[k], c = co[k];
        float4 vo = o4[i], vx = x4[i];
        vo.x = fmaxf(fmaf(a, vo.x, c) + vx.x, 0.f);
        vo.y = fmaxf(fmaf(a, vo.y, c) + vx.y, 0.f);
        vo.z = fmaxf(fmaf(a, vo.z, c) + vx.z, 0.f);
        vo.w = fmaxf(fmaf(a, vo.w, c) + vx.w, 0.f);
        o4[i] = vo;
    }
}

extern "C" void kernel_launch(void* const* d_in, const int* in_sizes, int n_in,
                              void* d_out, int out_size, void* d_ws, size_t ws_size,
                              hipStream_t stream)
{
    const float* x     = (const float*)d_in[0];
    const float* PA    = (const float*)d_in[1];
    const float* Wd    = (const float*)d_in[2];
    const float* gd    = (const float*)d_in[4];
    const float* betad = (const float*)d_in[5];
    const float* Wsub  = (const float*)d_in[6];
    const float* gsub  = (const float*)d_in[8];
    const float* betas = (const float*)d_in[9];
    const float* gout  = (const float*)d_in[10];
    const float* betao = (const float*)d_in[11];
    float* out = (float*)d_out;

    unsigned short* xdp  = (unsigned short*)d_ws;            // 39.3 MB
    unsigned short* zbuf = xdp + (size_t)3 * XDP_ELEMS;      // 65.5 MB, reused per layer
    float* st    = (float*)(zbuf + (size_t)Z_ELEMS);
    float* AC    = st + 96;
    float* stq   = AC + 96;       // [3][160]
    float* stout = stq + 480;     // [128]
    float* Wtg   = stout + 128;   // [64][48] transposed W_down

    hipMemsetAsync(st, 0, 800 * sizeof(float), stream);

    k_prep   <<<1,   256, 0, stream>>>(Wd, Wtg);
    k_down3  <<<800, 256, 0, stream>>>(x, Wtg, xdp, st);
    k_findown<<<1,    64, 0, stream>>>(st, gd, betad, AC);

    for (int l = 0; l < 3; l++) {
        k_z_mfma<<<1024, 256, 0, stream>>>(xdp + (size_t)l * XDP_ELEMS, PA + l * 3125,
                                           Wsub + l * 1280, AC + l * 16, AC + 48 + l * 16,
                                           zbuf, stq + l * 160);
        if (l == 0)
            k_apply<1, 0><<<2048, 256, 0, stream>>>(zbuf, stq + l * 160, gsub + l * 80,
                                                    betas + l * 80, out, stout);
        else if (l == 1)
            k_apply<0, 0><<<2048, 256, 0, stream>>>(zbuf, stq + l * 160, gsub + l * 80,
                                                    betas + l * 80, out, stout);
        else
            k_apply<0, 1><<<2048, 256, 0, stream>>>(zbuf, stq + l * 160, gsub + l * 80,
                                                    betas + l * 80, out, stout);
    }
    k_final<<<2048, 256, 0, stream>>>(x, gout, betao, stout, out);
}